// Round 1
// baseline (88.796 us; speedup 1.0000x reference)
//
#include <hip/hip_runtime.h>
#include <hip/hip_bf16.h>

typedef __attribute__((ext_vector_type(8))) short bf16x8;
typedef __attribute__((ext_vector_type(4))) float f32x4;
typedef unsigned short u16;

static constexpr int KDIM = 784;   // input features (28*28)
static constexpr int KP   = 800;   // K padded to multiple of 32
static constexpr int NDIM = 300;   // hidden size
static constexpr int NP   = 320;   // N padded to multiple of 16 (and 80 per wave)
static constexpr int DDIM = 10;    // output classes
static constexpr int BM   = 64;    // rows per block
static constexpr int BK   = 32;    // K per step
static constexpr int STR  = 40;    // LDS tile stride (bf16 elems), pads 32 -> 40 (2-way conflicts only)
static constexpr int H1STR = 328;  // h1 LDS stride (320 -> 328)
static constexpr int NSTEP = KP / BK; // 25

__device__ __forceinline__ u16 f2bf(float f) {
  unsigned u = __builtin_bit_cast(unsigned, f);
  u += 0x7fffu + ((u >> 16) & 1u);   // round-to-nearest-even
  return (u16)(u >> 16);
}

// ---- Kernel A: fold conv into the first linear layer ----
// Weff[j=(r,c)][n] = sum_{dr,dc} conv_w[dr][dc] * w1[((r-dr)*26 + (c-dc))*300 + n]
// stored transposed + padded as bf16: weff_t[n in 0..319][k in 0..799]
__global__ void build_weff(const float* __restrict__ cw,
                           const float* __restrict__ w1,
                           u16* __restrict__ weff) {
  int idx = blockIdx.x * 256 + threadIdx.x;
  if (idx >= NP * KP) return;
  int n = idx / KP;          // slow: n  (writes coalesced along k)
  int k = idx - n * KP;      // fast: k
  float acc = 0.f;
  if (n < NDIM && k < KDIM) {
    int r = k / 28, c = k - (k / 28) * 28;
    #pragma unroll
    for (int dr = 0; dr < 3; ++dr) {
      int orr = r - dr;
      if ((unsigned)orr < 26u) {
        #pragma unroll
        for (int dc = 0; dc < 3; ++dc) {
          int oc = c - dc;
          if ((unsigned)oc < 26u)
            acc += cw[dr * 3 + dc] * w1[(orr * 26 + oc) * NDIM + n];
        }
      }
    }
  }
  weff[n * KP + k] = f2bf(acc);
}

// ---- Kernel B: out = relu(x @ Weff + b1) @ w2 + b2, fused ----
__global__ void __launch_bounds__(256, 2)
fused_mlp(const float* __restrict__ x, const float* __restrict__ b1,
          const float* __restrict__ w2, const float* __restrict__ b2,
          const u16* __restrict__ weff, float* __restrict__ out) {
  // LDS overlay:
  //   main loop:  A tile [64][40] bf16 (5120 B) + B tile [320][40] bf16 (25600 B)
  //   epilogue:   H1 [64][328] bf16 (41984 B) + W2T [16][328] bf16 (10496 B)
  __shared__ __align__(16) u16 lds[26240]; // 52480 bytes
  u16* Alds = lds;
  u16* Blds = lds + BM * STR;
  u16* H1   = lds;
  u16* W2T  = lds + BM * H1STR;

  const int tid  = threadIdx.x;
  const int wv   = tid >> 6;       // wave 0..3, owns n-slice wv*80..+79
  const int lane = tid & 63;
  const int l16  = lane & 15;
  const int lhi  = lane >> 4;      // 0..3
  const int bm   = blockIdx.x * BM;

  const int arow = tid >> 2;            // 0..63
  const int ac8  = (tid & 3) << 3;      // 0,8,16,24
  const float* xrow = x + (size_t)(bm + arow) * KDIM;

  f32x4 acc[4][5];
  #pragma unroll
  for (int mi = 0; mi < 4; ++mi)
    #pragma unroll
    for (int ni = 0; ni < 5; ++ni)
      acc[mi][ni] = (f32x4){0.f, 0.f, 0.f, 0.f};

  auto loadA = [&](int k0) -> bf16x8 {
    int kc = k0 + ac8;
    bf16x8 r;
    if (kc + 8 <= KDIM) {              // kc multiple of 8, 784%8==0 -> clean split
      float4 v0 = *reinterpret_cast<const float4*>(xrow + kc);
      float4 v1 = *reinterpret_cast<const float4*>(xrow + kc + 4);
      r[0] = (short)f2bf(v0.x); r[1] = (short)f2bf(v0.y);
      r[2] = (short)f2bf(v0.z); r[3] = (short)f2bf(v0.w);
      r[4] = (short)f2bf(v1.x); r[5] = (short)f2bf(v1.y);
      r[6] = (short)f2bf(v1.z); r[7] = (short)f2bf(v1.w);
    } else {
      #pragma unroll
      for (int j = 0; j < 8; ++j) r[j] = 0;
    }
    return r;
  };

  auto loadB = [&](int k0, bf16x8* br) {
    #pragma unroll
    for (int i = 0; i < 5; ++i) {
      int ch = tid + i * 256;          // 0..1279
      int n  = ch >> 2;                // 0..319
      int c8 = (ch & 3) << 3;          // 0,8,16,24
      br[i] = *reinterpret_cast<const bf16x8*>(weff + n * KP + k0 + c8);
    }
  };

  // software pipeline: regs hold tile t while LDS holds tile t-1
  bf16x8 aReg = loadA(0);
  bf16x8 bReg[5];
  loadB(0, bReg);

  for (int t = 0; t < NSTEP; ++t) {
    // commit staged registers to LDS
    *reinterpret_cast<bf16x8*>(Alds + arow * STR + ac8) = aReg;
    #pragma unroll
    for (int i = 0; i < 5; ++i) {
      int ch = tid + i * 256;
      int n  = ch >> 2;
      int c8 = (ch & 3) << 3;
      *reinterpret_cast<bf16x8*>(Blds + n * STR + c8) = bReg[i];
    }
    __syncthreads();

    if (t + 1 < NSTEP) {               // prefetch next tile (in flight during MFMA)
      aReg = loadA((t + 1) * BK);
      loadB((t + 1) * BK, bReg);
    }

    bf16x8 af[4], bfr[5];
    #pragma unroll
    for (int mi = 0; mi < 4; ++mi)
      af[mi] = *reinterpret_cast<const bf16x8*>(Alds + (mi * 16 + l16) * STR + lhi * 8);
    #pragma unroll
    for (int ni = 0; ni < 5; ++ni)
      bfr[ni] = *reinterpret_cast<const bf16x8*>(Blds + (wv * 80 + ni * 16 + l16) * STR + lhi * 8);

    #pragma unroll
    for (int mi = 0; mi < 4; ++mi)
      #pragma unroll
      for (int ni = 0; ni < 5; ++ni)
        acc[mi][ni] = __builtin_amdgcn_mfma_f32_16x16x32_bf16(af[mi], bfr[ni], acc[mi][ni], 0, 0, 0);
    __syncthreads();
  }

  // ---- epilogue: h1 = relu(acc + b1) -> bf16 LDS; out = h1 @ w2 + b2 via MFMA ----
  // build transposed w2 in LDS: W2T[d][n] (d padded to 16, n padded to 320)
  for (int i = tid; i < 16 * NP; i += 256) {
    int d = i / NP, n = i - d * NP;
    float v = (d < DDIM && n < NDIM) ? w2[n * DDIM + d] : 0.f;
    W2T[d * H1STR + n] = f2bf(v);
  }
  #pragma unroll
  for (int mi = 0; mi < 4; ++mi) {
    #pragma unroll
    for (int ni = 0; ni < 5; ++ni) {
      int col  = wv * 80 + ni * 16 + l16;
      float bias = (col < NDIM) ? b1[col] : 0.f;
      int rbase = mi * 16 + lhi * 4;
      #pragma unroll
      for (int r = 0; r < 4; ++r) {
        float h = acc[mi][ni][r] + bias;
        H1[(rbase + r) * H1STR + col] = f2bf(fmaxf(h, 0.f));
      }
    }
  }
  __syncthreads();

  // each wave computes its 16 rows of out: [16][320] @ [320][16]
  f32x4 acc2 = (f32x4){0.f, 0.f, 0.f, 0.f};
  #pragma unroll
  for (int ks = 0; ks < NP / 32; ++ks) {
    bf16x8 a2 = *reinterpret_cast<const bf16x8*>(H1 + (wv * 16 + l16) * H1STR + ks * 32 + lhi * 8);
    bf16x8 b2f = *reinterpret_cast<const bf16x8*>(W2T + l16 * H1STR + ks * 32 + lhi * 8);
    acc2 = __builtin_amdgcn_mfma_f32_16x16x32_bf16(a2, b2f, acc2, 0, 0, 0);
  }
  if (l16 < DDIM) {
    float bb = b2[l16];
    #pragma unroll
    for (int r = 0; r < 4; ++r) {
      int row = bm + wv * 16 + lhi * 4 + r;
      out[row * DDIM + l16] = acc2[r] + bb;
    }
  }
}

extern "C" void kernel_launch(void* const* d_in, const int* in_sizes, int n_in,
                              void* d_out, int out_size, void* d_ws, size_t ws_size,
                              hipStream_t stream) {
  const float* x  = (const float*)d_in[0];
  const float* cw = (const float*)d_in[1];
  const float* w1 = (const float*)d_in[2];
  const float* b1 = (const float*)d_in[3];
  const float* w2 = (const float*)d_in[4];
  const float* b2 = (const float*)d_in[5];
  float* out = (float*)d_out;
  u16* weff = (u16*)d_ws;   // 320*800*2 = 512000 bytes

  hipLaunchKernelGGL(build_weff, dim3((NP * KP + 255) / 256), dim3(256), 0, stream,
                     cw, w1, weff);
  hipLaunchKernelGGL(fused_mlp, dim3(65536 / BM), dim3(256), 0, stream,
                     x, b1, w2, b2, weff, out);
}

// Round 2
// 79.962 us; speedup vs baseline: 1.1105x; 1.1105x over previous
//
#include <hip/hip_runtime.h>
#include <hip/hip_bf16.h>

typedef __attribute__((ext_vector_type(8))) short bf16x8;
typedef __attribute__((ext_vector_type(4))) float f32x4;
typedef unsigned short u16;

static constexpr int KDIM = 784;   // input features (28*28)
static constexpr int KP   = 800;   // K padded to multiple of 32 (ws stays 512000 B)
static constexpr int NDIM = 300;   // hidden size
static constexpr int NP   = 320;   // N padded
static constexpr int DDIM = 10;    // output classes
static constexpr int BM   = 64;    // rows per block
static constexpr int BK   = 32;    // K per step
static constexpr int NSTEP = KP / BK; // 25 (odd: 12 double-steps + 1 tail)
static constexpr int STR  = 40;    // A LDS stride (2-way conflicts only)
static constexpr int H1STR = 328;  // epilogue h1 stride

__device__ __forceinline__ u16 f2bf(float f) {
  unsigned u = __builtin_bit_cast(unsigned, f);
  u += 0x7fffu + ((u >> 16) & 1u);   // RNE
  return (u16)(u >> 16);
}

// ---- Kernel A: fold conv into first linear layer; weff_t[n][k] bf16, zero-padded ----
__global__ void build_weff(const float* __restrict__ cw,
                           const float* __restrict__ w1,
                           u16* __restrict__ weff) {
  int idx = blockIdx.x * 256 + threadIdx.x;
  if (idx >= NP * KP) return;
  int n = idx / KP;
  int k = idx - n * KP;
  float acc = 0.f;
  if (n < NDIM && k < KDIM) {
    int r = k / 28, c = k - (k / 28) * 28;
    #pragma unroll
    for (int dr = 0; dr < 3; ++dr) {
      int orr = r - dr;
      if ((unsigned)orr < 26u) {
        #pragma unroll
        for (int dc = 0; dc < 3; ++dc) {
          int oc = c - dc;
          if ((unsigned)oc < 26u)
            acc += cw[dr * 3 + dc] * w1[(orr * 26 + oc) * NDIM + n];
        }
      }
    }
  }
  weff[n * KP + k] = f2bf(acc);
}

// ---- Kernel B: out = relu(x @ Weff + b1) @ w2 + b2 ----
// A: LDS double-buffered (1 barrier/step), 2-step global prefetch.
// B: direct L2->register fragments, ping-ponged 1 step ahead (no LDS).
__global__ void __launch_bounds__(256, 3)
fused_mlp(const float* __restrict__ x, const float* __restrict__ b1,
          const float* __restrict__ w2, const float* __restrict__ b2,
          const u16* __restrict__ weff, float* __restrict__ out) {
  // LDS overlay: main loop A0[64][40] + A1[64][40] = 10240 B
  //              epilogue H1[32][328] (20992 B) + W2T[16][328] (10496 B) = 31488 B
  __shared__ __align__(16) u16 lds[15744];
  u16* A0  = lds;
  u16* A1  = lds + BM * STR;       // +2560 elems
  u16* H1  = lds;                   // epilogue overlay
  u16* W2T = lds + 32 * H1STR;      // +10496 elems

  const int tid  = threadIdx.x;
  const int wv   = tid >> 6;
  const int lane = tid & 63;
  const int l16  = lane & 15;
  const int lhi  = lane >> 4;       // 0..3
  const int bm   = blockIdx.x * BM;
  const int wvn  = wv * 80;

  const int arow = tid >> 2;              // 0..63
  const int ac8  = (tid & 3) << 3;        // 0,8,16,24
  const float* xrow = x + (size_t)(bm + arow) * KDIM;

  f32x4 acc[4][5];
  #pragma unroll
  for (int mi = 0; mi < 4; ++mi)
    #pragma unroll
    for (int ni = 0; ni < 5; ++ni)
      acc[mi][ni] = (f32x4){0.f, 0.f, 0.f, 0.f};

  float4 aV0, aV1;                  // fp32 staging for one A chunk (8 elems)
  auto loadA = [&](int k0) {
    int kc = k0 + ac8;
    if (kc + 8 <= KDIM) {
      aV0 = *reinterpret_cast<const float4*>(xrow + kc);
      aV1 = *reinterpret_cast<const float4*>(xrow + kc + 4);
    } else {
      aV0 = make_float4(0.f, 0.f, 0.f, 0.f);
      aV1 = make_float4(0.f, 0.f, 0.f, 0.f);
    }
  };
  auto commitA = [&](u16* buf) {
    bf16x8 r;
    r[0] = (short)f2bf(aV0.x); r[1] = (short)f2bf(aV0.y);
    r[2] = (short)f2bf(aV0.z); r[3] = (short)f2bf(aV0.w);
    r[4] = (short)f2bf(aV1.x); r[5] = (short)f2bf(aV1.y);
    r[6] = (short)f2bf(aV1.z); r[7] = (short)f2bf(aV1.w);
    *reinterpret_cast<bf16x8*>(buf + arow * STR + ac8) = r;
  };
  auto loadB = [&](int k0, bf16x8 (&br)[5]) {
    #pragma unroll
    for (int ni = 0; ni < 5; ++ni)
      br[ni] = *reinterpret_cast<const bf16x8*>(
          weff + (size_t)(wvn + ni * 16 + l16) * KP + k0 + lhi * 8);
  };
  auto doMFMA = [&](const u16* Ab, bf16x8 (&br)[5]) {
    bf16x8 af[4];
    #pragma unroll
    for (int mi = 0; mi < 4; ++mi)
      af[mi] = *reinterpret_cast<const bf16x8*>(Ab + (mi * 16 + l16) * STR + lhi * 8);
    #pragma unroll
    for (int mi = 0; mi < 4; ++mi)
      #pragma unroll
      for (int ni = 0; ni < 5; ++ni)
        acc[mi][ni] = __builtin_amdgcn_mfma_f32_16x16x32_bf16(af[mi], br[ni], acc[mi][ni], 0, 0, 0);
  };

  bf16x8 bE[5], bO[5];

  // prologue: tile0 -> A0; tile1 staged in regs; B tile0 in flight
  loadA(0);
  commitA(A0);
  loadA(BK);
  loadB(0, bE);
  __syncthreads();                  // A0 visible

  // 12 double-steps covering t = 0..23
  for (int tt = 0; tt < NSTEP - 1; tt += 2) {
    // even step t=tt: reads A0 + bE
    loadB((tt + 1) * BK, bO);       // B for t+1
    commitA(A1);                    // A tile tt+1 (loaded 1.5 steps ago)
    loadA((tt + 2) * BK);           // A tile tt+2 (committed next half)
    doMFMA(A0, bE);
    __syncthreads();
    // odd step t=tt+1: reads A1 + bO
    loadB((tt + 2) * BK, bE);       // B for t+2
    commitA(A0);                    // A tile tt+2
    if (tt + 3 < NSTEP) loadA((tt + 3) * BK);
    doMFMA(A1, bO);
    __syncthreads();
  }
  // tail step t=24: A0 holds tile 24 (committed at tt=22 odd half), bE = tile 24
  doMFMA(A0, bE);
  __syncthreads();

  // ---- epilogue ----
  // W2T[d][n] once (region disjoint from H1)
  for (int i = tid; i < 16 * NP; i += 256) {
    int d = i / NP, n = i - d * NP;
    float v = (d < DDIM && n < NDIM) ? w2[n * DDIM + d] : 0.f;
    W2T[d * H1STR + n] = f2bf(v);
  }

  float biasv[5];
  #pragma unroll
  for (int ni = 0; ni < 5; ++ni) {
    int col = wvn + ni * 16 + l16;
    biasv[ni] = (col < NDIM) ? b1[col] : 0.f;
  }

  // two passes of 32 rows each (keeps LDS high-water at 31.5 KB)
  #pragma unroll
  for (int p = 0; p < 2; ++p) {
    #pragma unroll
    for (int mi2 = 0; mi2 < 2; ++mi2) {
      int mi = 2 * p + mi2;
      #pragma unroll
      for (int ni = 0; ni < 5; ++ni) {
        int col = wvn + ni * 16 + l16;
        int rb  = mi2 * 16 + lhi * 4;
        #pragma unroll
        for (int r = 0; r < 4; ++r) {
          float h = acc[mi][ni][r] + biasv[ni];
          H1[(rb + r) * H1STR + col] = f2bf(fmaxf(h, 0.f));
        }
      }
    }
    __syncthreads();                // H1 (and on p==0, W2T) visible
    if (wv < 2) {
      f32x4 a2c = (f32x4){0.f, 0.f, 0.f, 0.f};
      #pragma unroll
      for (int ks = 0; ks < NP / 32; ++ks) {
        bf16x8 a2 = *reinterpret_cast<const bf16x8*>(H1 + (wv * 16 + l16) * H1STR + ks * 32 + lhi * 8);
        bf16x8 bw = *reinterpret_cast<const bf16x8*>(W2T + l16 * H1STR + ks * 32 + lhi * 8);
        a2c = __builtin_amdgcn_mfma_f32_16x16x32_bf16(a2, bw, a2c, 0, 0, 0);
      }
      if (l16 < DDIM) {
        float bb = b2[l16];
        #pragma unroll
        for (int r = 0; r < 4; ++r) {
          int row = bm + 32 * p + wv * 16 + lhi * 4 + r;
          out[(size_t)row * DDIM + l16] = a2c[r] + bb;
        }
      }
    }
    __syncthreads();                // before next pass overwrites H1
  }
}

extern "C" void kernel_launch(void* const* d_in, const int* in_sizes, int n_in,
                              void* d_out, int out_size, void* d_ws, size_t ws_size,
                              hipStream_t stream) {
  const float* x  = (const float*)d_in[0];
  const float* cw = (const float*)d_in[1];
  const float* w1 = (const float*)d_in[2];
  const float* b1 = (const float*)d_in[3];
  const float* w2 = (const float*)d_in[4];
  const float* b2 = (const float*)d_in[5];
  float* out = (float*)d_out;
  u16* weff = (u16*)d_ws;   // 320*800*2 = 512000 bytes

  hipLaunchKernelGGL(build_weff, dim3((NP * KP + 255) / 256), dim3(256), 0, stream,
                     cw, w1, weff);
  hipLaunchKernelGGL(fused_mlp, dim3(65536 / BM), dim3(256), 0, stream,
                     x, b1, w2, b2, weff, out);
}